// Round 12
// baseline (986.132 us; speedup 1.0000x reference)
//
#include <hip/hip_runtime.h>
#include <hip/hip_bf16.h>

#define NEXP   8
#define MTOK   4096
#define KDIM   2048
#define NINTER 5632
#define NPAIR  8192   // MTOK * TOPK

#define AS3 __attribute__((address_space(3)))
#define AS1 __attribute__((address_space(1)))

typedef __attribute__((ext_vector_type(4))) float f32x4;
typedef __attribute__((ext_vector_type(8))) short s16x8;

__device__ __forceinline__ short f2bf(float f) {
  union { float f; unsigned u; } v; v.f = f;
  unsigned r = v.u + 0x7FFFu + ((v.u >> 16) & 1u);
  return (short)(r >> 16);
}

__device__ __forceinline__ s16x8 pack8(float4 a, float4 b) {
  s16x8 v;
  v[0] = f2bf(a.x); v[1] = f2bf(a.y); v[2] = f2bf(a.z); v[3] = f2bf(a.w);
  v[4] = f2bf(b.x); v[5] = f2bf(b.y); v[6] = f2bf(b.z); v[7] = f2bf(b.w);
  return v;
}

// ============ fused: routing (block 0) + a1/w1 fp32->bf16 cvt (all blocks) ============
// cvt loops are branch-free, 64B-read / 32B-write per thread per iteration.
#define N16_A1 ((size_t)MTOK * KDIM / 16)                 // 524,288
#define N16_W1 ((size_t)NEXP * 2 * NINTER * KDIM / 16)    // 11,534,336
__global__ __launch_bounds__(256) void routecvt_k(const int* __restrict__ ids,
                                                  int* __restrict__ off,
                                                  int* __restrict__ list,
                                                  const float* __restrict__ a1,
                                                  unsigned short* __restrict__ a1b,
                                                  const float* __restrict__ w1,
                                                  unsigned short* __restrict__ w1b) {
  int tid = threadIdx.x;
  if (blockIdx.x == 0) {
    __shared__ int sids[NPAIR];
    __shared__ int scnt[64][8];
    __shared__ int sstart[64][8];
    __shared__ int s_is64;
    if (tid == 0) s_is64 = 1;
    __syncthreads();
    for (int i = tid; i < NPAIR / 2; i += 256)
      if (ids[2 * i + 1] != 0) s_is64 = 0;   // benign race, only writes 0
    __syncthreads();
    int is64 = s_is64;
    for (int i = tid; i < NPAIR; i += 256) {
      int e = is64 ? ids[2 * i] : ids[i];
      if (e < 0) e = 0; if (e > 7) e = 7;
      sids[i] = e;
    }
    if (tid < 64)
      for (int e = 0; e < 8; ++e) scnt[tid][e] = 0;
    __syncthreads();
    if (tid < 64) {
      int b0 = tid * 128;
      for (int i = 0; i < 128; ++i) ++scnt[tid][sids[b0 + i]];
    }
    __syncthreads();
    if (tid == 0) {
      int tot = 0;
      for (int e = 0; e < 8; ++e) {
        off[e] = tot;
        for (int c = 0; c < 64; ++c) { sstart[c][e] = tot; tot += scnt[c][e]; }
      }
      off[8] = tot;
    }
    __syncthreads();
    if (tid < 64) {
      int b0 = tid * 128;
      for (int i = 0; i < 128; ++i) {
        int p = b0 + i;
        int e = sids[p];
        list[sstart[tid][e]++] = p;    // stable within chunk -> deterministic
      }
    }
  }
  size_t gid = (size_t)blockIdx.x * 256 + tid;
  size_t stride = (size_t)gridDim.x * 256;
  for (size_t i = gid; i < N16_A1; i += stride) {
    const float4* p = (const float4*)(a1 + i * 16);
    float4 f0 = p[0], f1 = p[1], f2 = p[2], f3 = p[3];
    s16x8* d = (s16x8*)(a1b + i * 16);
    d[0] = pack8(f0, f1);
    d[1] = pack8(f2, f3);
  }
  for (size_t i = gid; i < N16_W1; i += stride) {
    const float4* p = (const float4*)(w1 + i * 16);
    float4 f0 = p[0], f1 = p[1], f2 = p[2], f3 = p[3];
    s16x8* d = (s16x8*)(w1b + i * 16);
    d[0] = pack8(f0, f1);
    d[1] = pack8(f2, f3);
  }
}

// ---------------- GEMM1: act[slot,:] = silu(a1@Wg^T) * (a1@Wu^T) ----------------
// Grid (44,64,8), x = nt (measured-best ordering). BF=1: bf16 sources + global_load_lds.
// w2 fp32->bf16 cvt spread over ALL 22528 blocks: 512 groups (2/thread) each
// (22528 x 512 = 11,534,336 = whole w2, exactly). Working blocks interleave the
// 2 groups at K-steps 0 and 16 with T14 split (load before barrier, pack+store
// after); early-exit blocks do their slice in a short tight loop (~2-3 us) that
// co-schedules with resident GEMM blocks at wave level. BF=0: fp32 fallback.
template <int BF>
__global__ __launch_bounds__(256, 2) void gemm1_t(const float* __restrict__ a1,
                                                  const unsigned short* __restrict__ a1b,
                                                  const float* __restrict__ w1,
                                                  const unsigned short* __restrict__ w1b,
                                                  const float* __restrict__ w2f,
                                                  unsigned short* __restrict__ w2b,
                                                  const int* __restrict__ off,
                                                  const int* __restrict__ list,
                                                  unsigned short* __restrict__ act) {
  int e = blockIdx.z, mt = blockIdx.y, nt = blockIdx.x;
  int tid = threadIdx.x;
  int base = off[e];
  int cnt  = off[e + 1] - base;

  size_t cb = 0;
  if constexpr (BF) {
    size_t bid = (size_t)nt + 44u * ((size_t)mt + 64u * (size_t)e);
    cb = bid * 512;
  }

  if (mt * 128 >= cnt) {
    if constexpr (BF) {
      // early-exit block: convert its 512-group slice (2 groups/thread) and leave
#pragma unroll
      for (int s = 0; s < 2; ++s) {
        size_t g = cb + (size_t)s * 256 + tid;
        const float4* p = (const float4*)(w2f + g * 8);
        float4 f0 = p[0], f1 = p[1];
        *(s16x8*)(w2b + g * 8) = pack8(f0, f1);
      }
    }
    return;
  }

  __shared__ __align__(16) short lA[128 * 64];
  __shared__ __align__(16) short lBg[128 * 64];
  __shared__ __align__(16) short lBu[128 * 64];
  __shared__ int srow[128];
  if (tid < 128) {
    int r = mt * 128 + tid;
    srow[tid] = (r < cnt) ? (list[base + r] >> 1) : 0;
  }
  __syncthreads();
  int lane = tid & 63, wave = tid >> 6;
  int wm = wave >> 1, wn = wave & 1;
  int lrow = lane & 15, lhi = lane >> 4;
  f32x4 accg[4][4], accu[4][4];
#pragma unroll
  for (int i = 0; i < 4; ++i)
#pragma unroll
    for (int j = 0; j < 4; ++j) { accg[i][j] = (f32x4)(0.f); accu[i][j] = (f32x4)(0.f); }
  int n0 = nt * 128;

  const unsigned short* aSrc[4];
  const unsigned short* gSrc[4];
  const unsigned short* uSrc[4];
  if constexpr (BF) {
    const unsigned short* w1be = w1b + (size_t)e * (2 * NINTER) * KDIM;
    int c = lane & 7;
#pragma unroll
    for (int q = 0; q < 4; ++q) {
      int r = wave * 32 + q * 8 + (lane >> 3);       // LDS row this lane feeds
      int swz = (c ^ (r & 7)) * 8;                   // pre-swizzled source chunk
      aSrc[q] = a1b + (size_t)srow[r] * KDIM + swz;
      gSrc[q] = w1be + (size_t)(n0 + r) * KDIM + swz;
      uSrc[q] = w1be + (size_t)(NINTER + n0 + r) * KDIM + swz;
    }
  }
  const float* w1e = w1 + (size_t)e * (2 * NINTER) * KDIM;

  for (int k0 = 0; k0 < KDIM; k0 += 64) {
    float4 cvf0, cvf1;
    size_t cvg = 0;
    bool docv = false;
    if constexpr (BF) {
#pragma unroll
      for (int q = 0; q < 4; ++q) {
        int row0 = wave * 32 + q * 8;
        __builtin_amdgcn_global_load_lds((const AS1 void*)(aSrc[q] + k0), (AS3 void*)&lA[row0 * 64], 16, 0, 0);
        __builtin_amdgcn_global_load_lds((const AS1 void*)(gSrc[q] + k0), (AS3 void*)&lBg[row0 * 64], 16, 0, 0);
        __builtin_amdgcn_global_load_lds((const AS1 void*)(uSrc[q] + k0), (AS3 void*)&lBu[row0 * 64], 16, 0, 0);
      }
      // w2 cvt: LOAD only, at K-steps 0 and 16 (2 groups/thread total)
      int ks = k0 >> 6;
      docv = ((ks & 15) == 0);
      if (docv) {
        cvg = cb + (size_t)(ks >> 4) * 256 + tid;
        const float4* p = (const float4*)(w2f + cvg * 8);
        cvf0 = p[0];
        cvf1 = p[1];
      }
    } else {
#pragma unroll
      for (int c4 = 0; c4 < 4; ++c4) {
        int cid = c4 * 256 + tid;
        int row = cid >> 3, k8 = cid & 7;
        const float* s = a1 + (size_t)srow[row] * KDIM + k0 + k8 * 8;
        float4 f0 = *(const float4*)s;
        float4 f1 = *(const float4*)(s + 4);
        *(s16x8*)&lA[row * 64 + ((k8 ^ (row & 7)) * 8)] = pack8(f0, f1);
      }
#pragma unroll
      for (int c4 = 0; c4 < 4; ++c4) {
        int cid = c4 * 256 + tid;
        int row = cid >> 3, k8 = cid & 7;
        const float* sg = w1e + (size_t)(n0 + row) * KDIM + k0 + k8 * 8;
        const float* su = w1e + (size_t)(NINTER + n0 + row) * KDIM + k0 + k8 * 8;
        float4 g0 = *(const float4*)sg;
        float4 g1 = *(const float4*)(sg + 4);
        float4 u0 = *(const float4*)su;
        float4 u1 = *(const float4*)(su + 4);
        int o = row * 64 + ((k8 ^ (row & 7)) * 8);
        *(s16x8*)&lBg[o] = pack8(g0, g1);
        *(s16x8*)&lBu[o] = pack8(u0, u1);
      }
    }
    __syncthreads();
    if constexpr (BF) {
      // w2 cvt: pack + STORE after the barrier; retires under the MFMA phase.
      if (docv) *(s16x8*)(w2b + cvg * 8) = pack8(cvf0, cvf1);
    }
#pragma unroll
    for (int kk = 0; kk < 2; ++kk) {
      s16x8 af[4], bg[4], bu[4];
      int chunk = kk * 4 + lhi;
#pragma unroll
      for (int i = 0; i < 4; ++i) {
        int r = wm * 64 + i * 16 + lrow;
        af[i] = *(const s16x8*)&lA[r * 64 + ((chunk ^ (r & 7)) * 8)];
      }
#pragma unroll
      for (int j = 0; j < 4; ++j) {
        int r = wn * 64 + j * 16 + lrow;
        int o = r * 64 + ((chunk ^ (r & 7)) * 8);
        bg[j] = *(const s16x8*)&lBg[o];
        bu[j] = *(const s16x8*)&lBu[o];
      }
#pragma unroll
      for (int i = 0; i < 4; ++i)
#pragma unroll
        for (int j = 0; j < 4; ++j) {
          accg[i][j] = __builtin_amdgcn_mfma_f32_16x16x32_bf16(af[i], bg[j], accg[i][j], 0, 0, 0);
          accu[i][j] = __builtin_amdgcn_mfma_f32_16x16x32_bf16(af[i], bu[j], accu[i][j], 0, 0, 0);
        }
    }
    __syncthreads();
  }
#pragma unroll
  for (int i = 0; i < 4; ++i) {
#pragma unroll
    for (int q = 0; q < 4; ++q) {
      int r = wm * 64 + i * 16 + lhi * 4 + q;
      int grow = mt * 128 + r;
      if (grow < cnt) {
        size_t rowoff = (size_t)(base + grow) * NINTER;
#pragma unroll
        for (int j = 0; j < 4; ++j) {
          float g = accg[i][j][q], u = accu[i][j][q];
          float a = (g / (1.f + __expf(-g))) * u;
          int col = n0 + wn * 64 + j * 16 + lrow;
          act[rowoff + col] = (unsigned short)f2bf(a);
        }
      }
    }
  }
}

// ---------------- GEMM2: out[token,:] += tw * (act @ w2[e]^T) ----------------
// Grid (16,64,8), x = nt: same-panel m-blocks at stride 16 (≡0 mod 8) -> one XCD
// per panel (measured 222 us). Keep exactly.
template <int BF>
__global__ __launch_bounds__(256, 2) void gemm2_t(const unsigned short* __restrict__ act,
                                                  const float* __restrict__ w2,
                                                  const unsigned short* __restrict__ w2b,
                                                  const int* __restrict__ off,
                                                  const int* __restrict__ list,
                                                  const float* __restrict__ tw,
                                                  float* __restrict__ out) {
  int e = blockIdx.z, mt = blockIdx.y, nt = blockIdx.x;
  int base = off[e];
  int cnt  = off[e + 1] - base;
  if (mt * 128 >= cnt) return;
  __shared__ __align__(16) short lA[128 * 64];
  __shared__ __align__(16) short lB[128 * 64];
  int tid = threadIdx.x;
  int lane = tid & 63, wave = tid >> 6;
  int wm = wave >> 1, wn = wave & 1;
  int lrow = lane & 15, lhi = lane >> 4;
  f32x4 acc[4][4];
#pragma unroll
  for (int i = 0; i < 4; ++i)
#pragma unroll
    for (int j = 0; j < 4; ++j) acc[i][j] = (f32x4)(0.f);
  const float* w2e = w2 + (size_t)e * KDIM * NINTER;

  const unsigned short* aSrc[4];
  const unsigned short* bSrc[4];
  if constexpr (BF) {
    const unsigned short* w2be = w2b + (size_t)e * KDIM * NINTER;
    int c = lane & 7;
#pragma unroll
    for (int q = 0; q < 4; ++q) {
      int r = wave * 32 + q * 8 + (lane >> 3);
      int swz = (c ^ (r & 7)) * 8;
      int grow = mt * 128 + r;
      if (grow >= cnt) grow = cnt - 1;
      aSrc[q] = act + (size_t)(base + grow) * NINTER + swz;
      bSrc[q] = w2be + (size_t)(nt * 128 + r) * NINTER + swz;
    }
  }

  for (int k0 = 0; k0 < NINTER; k0 += 64) {
    if constexpr (BF) {
#pragma unroll
      for (int q = 0; q < 4; ++q) {
        int row0 = wave * 32 + q * 8;
        __builtin_amdgcn_global_load_lds((const AS1 void*)(aSrc[q] + k0), (AS3 void*)&lA[row0 * 64], 16, 0, 0);
        __builtin_amdgcn_global_load_lds((const AS1 void*)(bSrc[q] + k0), (AS3 void*)&lB[row0 * 64], 16, 0, 0);
      }
    } else {
#pragma unroll
      for (int c4 = 0; c4 < 4; ++c4) {
        int cid = c4 * 256 + tid;
        int row = cid >> 3, k8 = cid & 7;
        int grow = mt * 128 + row;
        if (grow >= cnt) grow = cnt - 1;
        s16x8 v = *(const s16x8*)(act + (size_t)(base + grow) * NINTER + k0 + k8 * 8);
        *(s16x8*)&lA[row * 64 + ((k8 ^ (row & 7)) * 8)] = v;
      }
#pragma unroll
      for (int c4 = 0; c4 < 4; ++c4) {
        int cid = c4 * 256 + tid;
        int row = cid >> 3, k8 = cid & 7;
        const float* s = w2e + (size_t)(nt * 128 + row) * NINTER + k0 + k8 * 8;
        float4 f0 = *(const float4*)s;
        float4 f1 = *(const float4*)(s + 4);
        *(s16x8*)&lB[row * 64 + ((k8 ^ (row & 7)) * 8)] = pack8(f0, f1);
      }
    }
    __syncthreads();
#pragma unroll
    for (int kk = 0; kk < 2; ++kk) {
      s16x8 af[4], bf[4];
      int chunk = kk * 4 + lhi;
#pragma unroll
      for (int i = 0; i < 4; ++i) {
        int r = wm * 64 + i * 16 + lrow;
        af[i] = *(const s16x8*)&lA[r * 64 + ((chunk ^ (r & 7)) * 8)];
      }
#pragma unroll
      for (int j = 0; j < 4; ++j) {
        int r = wn * 64 + j * 16 + lrow;
        bf[j] = *(const s16x8*)&lB[r * 64 + ((chunk ^ (r & 7)) * 8)];
      }
#pragma unroll
      for (int i = 0; i < 4; ++i)
#pragma unroll
        for (int j = 0; j < 4; ++j)
          acc[i][j] = __builtin_amdgcn_mfma_f32_16x16x32_bf16(af[i], bf[j], acc[i][j], 0, 0, 0);
    }
    __syncthreads();
  }
#pragma unroll
  for (int i = 0; i < 4; ++i) {
#pragma unroll
    for (int q = 0; q < 4; ++q) {
      int r = wm * 64 + i * 16 + lhi * 4 + q;
      int grow = mt * 128 + r;
      if (grow < cnt) {
        int p = list[base + grow];
        int m = p >> 1;
        float wgt = tw[p];
#pragma unroll
        for (int j = 0; j < 4; ++j) {
          int col = nt * 128 + wn * 64 + j * 16 + lrow;
          atomicAdd(&out[(size_t)m * KDIM + col], wgt * acc[i][j][q]);
        }
      }
    }
  }
}

// standalone route kernel for the fallback path
__global__ __launch_bounds__(512) void route_k(const int* __restrict__ ids,
                                               int* __restrict__ off,
                                               int* __restrict__ list) {
  __shared__ int sids[NPAIR];
  __shared__ int scnt[64][8];
  __shared__ int sstart[64][8];
  __shared__ int s_is64;
  int tid = threadIdx.x;
  if (tid == 0) s_is64 = 1;
  __syncthreads();
  for (int i = tid; i < NPAIR / 2; i += 512)
    if (ids[2 * i + 1] != 0) s_is64 = 0;
  __syncthreads();
  int is64 = s_is64;
  for (int i = tid; i < NPAIR; i += 512) {
    int e = is64 ? ids[2 * i] : ids[i];
    if (e < 0) e = 0; if (e > 7) e = 7;
    sids[i] = e;
  }
  if (tid < 64)
    for (int e = 0; e < 8; ++e) scnt[tid][e] = 0;
  __syncthreads();
  if (tid < 64) {
    int b0 = tid * 128;
    for (int i = 0; i < 128; ++i) ++scnt[tid][sids[b0 + i]];
  }
  __syncthreads();
  if (tid == 0) {
    int tot = 0;
    for (int e = 0; e < 8; ++e) {
      off[e] = tot;
      for (int c = 0; c < 64; ++c) { sstart[c][e] = tot; tot += scnt[c][e]; }
    }
    off[8] = tot;
  }
  __syncthreads();
  if (tid < 64) {
    int b0 = tid * 128;
    for (int i = 0; i < 128; ++i) {
      int p = b0 + i;
      int e = sids[p];
      list[sstart[tid][e]++] = p;
    }
  }
}

extern "C" void kernel_launch(void* const* d_in, const int* in_sizes, int n_in,
                              void* d_out, int out_size, void* d_ws, size_t ws_size,
                              hipStream_t stream) {
  const float* a1 = (const float*)d_in[0];
  const float* w1 = (const float*)d_in[1];
  const float* w2 = (const float*)d_in[2];
  const float* tw = (const float*)d_in[3];
  const int*   ids = (const int*)d_in[4];
  float* out = (float*)d_out;

  int* off  = (int*)d_ws;
  int* list = off + 16;
  unsigned short* act = (unsigned short*)((char*)d_ws + 65536);
  size_t actB = (size_t)NPAIR * NINTER * 2;
  unsigned short* a1b = (unsigned short*)((char*)act + actB);
  size_t a1B = (size_t)MTOK * KDIM * 2;
  unsigned short* w1b = (unsigned short*)((char*)a1b + a1B);
  size_t w1B = (size_t)NEXP * 2 * NINTER * KDIM * 2;
  unsigned short* w2b = (unsigned short*)((char*)w1b + w1B);
  size_t w2B = (size_t)NEXP * KDIM * NINTER * 2;
  size_t need = 65536 + actB + a1B + w1B + w2B;

  hipMemsetAsync(d_out, 0, (size_t)MTOK * KDIM * sizeof(float), stream);

  if (ws_size >= need) {
    routecvt_k<<<4096, 256, 0, stream>>>(ids, off, list, a1, a1b, w1, w1b);
    gemm1_t<1><<<dim3(NINTER / 128, 64, NEXP), 256, 0, stream>>>(a1, a1b, w1, w1b, w2, w2b, off, list, act);
    gemm2_t<1><<<dim3(KDIM / 128, 64, NEXP), 256, 0, stream>>>(act, w2, w2b, off, list, tw, out);
  } else {
    route_k<<<1, 512, 0, stream>>>(ids, off, list);
    gemm1_t<0><<<dim3(NINTER / 128, 64, NEXP), 256, 0, stream>>>(a1, a1b, w1, w1b, w2, w2b, off, list, act);
    gemm2_t<0><<<dim3(KDIM / 128, 64, NEXP), 256, 0, stream>>>(act, w2, w2b, off, list, tw, out);
  }
}

// Round 13
// 969.172 us; speedup vs baseline: 1.0175x; 1.0175x over previous
//
#include <hip/hip_runtime.h>
#include <hip/hip_bf16.h>

#define NEXP   8
#define MTOK   4096
#define KDIM   2048
#define NINTER 5632
#define NPAIR  8192   // MTOK * TOPK

#define AS3 __attribute__((address_space(3)))
#define AS1 __attribute__((address_space(1)))

typedef __attribute__((ext_vector_type(4))) float f32x4;
typedef __attribute__((ext_vector_type(8))) short s16x8;

__device__ __forceinline__ short f2bf(float f) {
  union { float f; unsigned u; } v; v.f = f;
  unsigned r = v.u + 0x7FFFu + ((v.u >> 16) & 1u);
  return (short)(r >> 16);
}

__device__ __forceinline__ s16x8 pack8(float4 a, float4 b) {
  s16x8 v;
  v[0] = f2bf(a.x); v[1] = f2bf(a.y); v[2] = f2bf(a.z); v[3] = f2bf(a.w);
  v[4] = f2bf(b.x); v[5] = f2bf(b.y); v[6] = f2bf(b.z); v[7] = f2bf(b.w);
  return v;
}

// ============ fused: routing (block 0) + a1/w1 fp32->bf16 cvt (all blocks) ============
// cvt loops are branch-free, 64B-read / 32B-write per thread per iteration.
#define N16_A1 ((size_t)MTOK * KDIM / 16)                 // 524,288
#define N16_W1 ((size_t)NEXP * 2 * NINTER * KDIM / 16)    // 11,534,336
__global__ __launch_bounds__(256) void routecvt_k(const int* __restrict__ ids,
                                                  int* __restrict__ off,
                                                  int* __restrict__ list,
                                                  const float* __restrict__ a1,
                                                  unsigned short* __restrict__ a1b,
                                                  const float* __restrict__ w1,
                                                  unsigned short* __restrict__ w1b) {
  int tid = threadIdx.x;
  if (blockIdx.x == 0) {
    __shared__ int sids[NPAIR];
    __shared__ int scnt[64][8];
    __shared__ int sstart[64][8];
    __shared__ int s_is64;
    if (tid == 0) s_is64 = 1;
    __syncthreads();
    for (int i = tid; i < NPAIR / 2; i += 256)
      if (ids[2 * i + 1] != 0) s_is64 = 0;   // benign race, only writes 0
    __syncthreads();
    int is64 = s_is64;
    for (int i = tid; i < NPAIR; i += 256) {
      int e = is64 ? ids[2 * i] : ids[i];
      if (e < 0) e = 0; if (e > 7) e = 7;
      sids[i] = e;
    }
    if (tid < 64)
      for (int e = 0; e < 8; ++e) scnt[tid][e] = 0;
    __syncthreads();
    if (tid < 64) {
      int b0 = tid * 128;
      for (int i = 0; i < 128; ++i) ++scnt[tid][sids[b0 + i]];
    }
    __syncthreads();
    if (tid == 0) {
      int tot = 0;
      for (int e = 0; e < 8; ++e) {
        off[e] = tot;
        for (int c = 0; c < 64; ++c) { sstart[c][e] = tot; tot += scnt[c][e]; }
      }
      off[8] = tot;
    }
    __syncthreads();
    if (tid < 64) {
      int b0 = tid * 128;
      for (int i = 0; i < 128; ++i) {
        int p = b0 + i;
        int e = sids[p];
        list[sstart[tid][e]++] = p;    // stable within chunk -> deterministic
      }
    }
  }
  size_t gid = (size_t)blockIdx.x * 256 + tid;
  size_t stride = (size_t)gridDim.x * 256;
  for (size_t i = gid; i < N16_A1; i += stride) {
    const float4* p = (const float4*)(a1 + i * 16);
    float4 f0 = p[0], f1 = p[1], f2 = p[2], f3 = p[3];
    s16x8* d = (s16x8*)(a1b + i * 16);
    d[0] = pack8(f0, f1);
    d[1] = pack8(f2, f3);
  }
  for (size_t i = gid; i < N16_W1; i += stride) {
    const float4* p = (const float4*)(w1 + i * 16);
    float4 f0 = p[0], f1 = p[1], f2 = p[2], f3 = p[3];
    s16x8* d = (s16x8*)(w1b + i * 16);
    d[0] = pack8(f0, f1);
    d[1] = pack8(f2, f3);
  }
}

// ---------------- GEMM1: act[slot,:] = silu(a1@Wg^T) * (a1@Wu^T) ----------------
// Grid (44,64,8), x = nt (measured-best ordering). BF=1: bf16 sources + global_load_lds;
// carrier blocks (mt<8) also convert a 4096-group slice of w2 interleaved into the K-loop
// (2816 x 4096 = whole w2). T14 split: cvt LOAD issues before the staging barrier (drains
// in the shared vmcnt window), pack+STORE issue after it (retire under the MFMA phase).
// BF=0: fp32 fallback.
template <int BF>
__global__ __launch_bounds__(256, 2) void gemm1_t(const float* __restrict__ a1,
                                                  const unsigned short* __restrict__ a1b,
                                                  const float* __restrict__ w1,
                                                  const unsigned short* __restrict__ w1b,
                                                  const float* __restrict__ w2f,
                                                  unsigned short* __restrict__ w2b,
                                                  const int* __restrict__ off,
                                                  const int* __restrict__ list,
                                                  unsigned short* __restrict__ act) {
  int e = blockIdx.z, mt = blockIdx.y, nt = blockIdx.x;
  int tid = threadIdx.x;
  int base = off[e];
  int cnt  = off[e + 1] - base;

  bool carrier = false;
  size_t cb = 0;
  if constexpr (BF) {
    carrier = (mt < 8);
    cb = ((size_t)nt + 44u * ((size_t)mt + 8u * (size_t)e)) * 4096;
  }

  if (mt * 128 >= cnt) {
    if constexpr (BF) {
      if (carrier) {   // rare: expert with <1024 slots; do slice in a tight loop
        for (int s = 0; s < 16; ++s) {
          size_t g = cb + (size_t)s * 256 + tid;
          const float4* p = (const float4*)(w2f + g * 8);
          float4 f0 = p[0], f1 = p[1];
          *(s16x8*)(w2b + g * 8) = pack8(f0, f1);
        }
      }
    }
    return;
  }

  __shared__ __align__(16) short lA[128 * 64];
  __shared__ __align__(16) short lBg[128 * 64];
  __shared__ __align__(16) short lBu[128 * 64];
  __shared__ int srow[128];
  if (tid < 128) {
    int r = mt * 128 + tid;
    srow[tid] = (r < cnt) ? (list[base + r] >> 1) : 0;
  }
  __syncthreads();
  int lane = tid & 63, wave = tid >> 6;
  int wm = wave >> 1, wn = wave & 1;
  int lrow = lane & 15, lhi = lane >> 4;
  f32x4 accg[4][4], accu[4][4];
#pragma unroll
  for (int i = 0; i < 4; ++i)
#pragma unroll
    for (int j = 0; j < 4; ++j) { accg[i][j] = (f32x4)(0.f); accu[i][j] = (f32x4)(0.f); }
  int n0 = nt * 128;

  const unsigned short* aSrc[4];
  const unsigned short* gSrc[4];
  const unsigned short* uSrc[4];
  if constexpr (BF) {
    const unsigned short* w1be = w1b + (size_t)e * (2 * NINTER) * KDIM;
    int c = lane & 7;
#pragma unroll
    for (int q = 0; q < 4; ++q) {
      int r = wave * 32 + q * 8 + (lane >> 3);       // LDS row this lane feeds
      int swz = (c ^ (r & 7)) * 8;                   // pre-swizzled source chunk
      aSrc[q] = a1b + (size_t)srow[r] * KDIM + swz;
      gSrc[q] = w1be + (size_t)(n0 + r) * KDIM + swz;
      uSrc[q] = w1be + (size_t)(NINTER + n0 + r) * KDIM + swz;
    }
  }
  const float* w1e = w1 + (size_t)e * (2 * NINTER) * KDIM;

  for (int k0 = 0; k0 < KDIM; k0 += 64) {
    float4 cvf0, cvf1;
    size_t cvg = 0;
    bool docv = false;
    if constexpr (BF) {
#pragma unroll
      for (int q = 0; q < 4; ++q) {
        int row0 = wave * 32 + q * 8;
        __builtin_amdgcn_global_load_lds((const AS1 void*)(aSrc[q] + k0), (AS3 void*)&lA[row0 * 64], 16, 0, 0);
        __builtin_amdgcn_global_load_lds((const AS1 void*)(gSrc[q] + k0), (AS3 void*)&lBg[row0 * 64], 16, 0, 0);
        __builtin_amdgcn_global_load_lds((const AS1 void*)(uSrc[q] + k0), (AS3 void*)&lBu[row0 * 64], 16, 0, 0);
      }
      // w2 cvt: LOAD only (drains in the same vmcnt window as the staging loads)
      int ks = k0 >> 6;
      docv = carrier && ((ks & 1) == 0);
      if (docv) {
        cvg = cb + (size_t)(ks >> 1) * 256 + tid;
        const float4* p = (const float4*)(w2f + cvg * 8);
        cvf0 = p[0];
        cvf1 = p[1];
      }
    } else {
#pragma unroll
      for (int c4 = 0; c4 < 4; ++c4) {
        int cid = c4 * 256 + tid;
        int row = cid >> 3, k8 = cid & 7;
        const float* s = a1 + (size_t)srow[row] * KDIM + k0 + k8 * 8;
        float4 f0 = *(const float4*)s;
        float4 f1 = *(const float4*)(s + 4);
        *(s16x8*)&lA[row * 64 + ((k8 ^ (row & 7)) * 8)] = pack8(f0, f1);
      }
#pragma unroll
      for (int c4 = 0; c4 < 4; ++c4) {
        int cid = c4 * 256 + tid;
        int row = cid >> 3, k8 = cid & 7;
        const float* sg = w1e + (size_t)(n0 + row) * KDIM + k0 + k8 * 8;
        const float* su = w1e + (size_t)(NINTER + n0 + row) * KDIM + k0 + k8 * 8;
        float4 g0 = *(const float4*)sg;
        float4 g1 = *(const float4*)(sg + 4);
        float4 u0 = *(const float4*)su;
        float4 u1 = *(const float4*)(su + 4);
        int o = row * 64 + ((k8 ^ (row & 7)) * 8);
        *(s16x8*)&lBg[o] = pack8(g0, g1);
        *(s16x8*)&lBu[o] = pack8(u0, u1);
      }
    }
    __syncthreads();
    if constexpr (BF) {
      // w2 cvt: pack + STORE after the barrier; retires under the MFMA phase.
      if (docv) *(s16x8*)(w2b + cvg * 8) = pack8(cvf0, cvf1);
    }
#pragma unroll
    for (int kk = 0; kk < 2; ++kk) {
      s16x8 af[4], bg[4], bu[4];
      int chunk = kk * 4 + lhi;
#pragma unroll
      for (int i = 0; i < 4; ++i) {
        int r = wm * 64 + i * 16 + lrow;
        af[i] = *(const s16x8*)&lA[r * 64 + ((chunk ^ (r & 7)) * 8)];
      }
#pragma unroll
      for (int j = 0; j < 4; ++j) {
        int r = wn * 64 + j * 16 + lrow;
        int o = r * 64 + ((chunk ^ (r & 7)) * 8);
        bg[j] = *(const s16x8*)&lBg[o];
        bu[j] = *(const s16x8*)&lBu[o];
      }
#pragma unroll
      for (int i = 0; i < 4; ++i)
#pragma unroll
        for (int j = 0; j < 4; ++j) {
          accg[i][j] = __builtin_amdgcn_mfma_f32_16x16x32_bf16(af[i], bg[j], accg[i][j], 0, 0, 0);
          accu[i][j] = __builtin_amdgcn_mfma_f32_16x16x32_bf16(af[i], bu[j], accu[i][j], 0, 0, 0);
        }
    }
    __syncthreads();
  }
#pragma unroll
  for (int i = 0; i < 4; ++i) {
#pragma unroll
    for (int q = 0; q < 4; ++q) {
      int r = wm * 64 + i * 16 + lhi * 4 + q;
      int grow = mt * 128 + r;
      if (grow < cnt) {
        size_t rowoff = (size_t)(base + grow) * NINTER;
#pragma unroll
        for (int j = 0; j < 4; ++j) {
          float g = accg[i][j][q], u = accu[i][j][q];
          float a = (g / (1.f + __expf(-g))) * u;
          int col = n0 + wn * 64 + j * 16 + lrow;
          act[rowoff + col] = (unsigned short)f2bf(a);
        }
      }
    }
  }
}

// ---------------- GEMM2: out[token,:] += tw * (act @ w2[e]^T) ----------------
// Grid (16,64,8), x = nt: same-panel m-blocks at stride 16 (≡0 mod 8) -> one XCD
// per panel (measured 222 us). Keep exactly.
template <int BF>
__global__ __launch_bounds__(256, 2) void gemm2_t(const unsigned short* __restrict__ act,
                                                  const float* __restrict__ w2,
                                                  const unsigned short* __restrict__ w2b,
                                                  const int* __restrict__ off,
                                                  const int* __restrict__ list,
                                                  const float* __restrict__ tw,
                                                  float* __restrict__ out) {
  int e = blockIdx.z, mt = blockIdx.y, nt = blockIdx.x;
  int base = off[e];
  int cnt  = off[e + 1] - base;
  if (mt * 128 >= cnt) return;
  __shared__ __align__(16) short lA[128 * 64];
  __shared__ __align__(16) short lB[128 * 64];
  int tid = threadIdx.x;
  int lane = tid & 63, wave = tid >> 6;
  int wm = wave >> 1, wn = wave & 1;
  int lrow = lane & 15, lhi = lane >> 4;
  f32x4 acc[4][4];
#pragma unroll
  for (int i = 0; i < 4; ++i)
#pragma unroll
    for (int j = 0; j < 4; ++j) acc[i][j] = (f32x4)(0.f);
  const float* w2e = w2 + (size_t)e * KDIM * NINTER;

  const unsigned short* aSrc[4];
  const unsigned short* bSrc[4];
  if constexpr (BF) {
    const unsigned short* w2be = w2b + (size_t)e * KDIM * NINTER;
    int c = lane & 7;
#pragma unroll
    for (int q = 0; q < 4; ++q) {
      int r = wave * 32 + q * 8 + (lane >> 3);
      int swz = (c ^ (r & 7)) * 8;
      int grow = mt * 128 + r;
      if (grow >= cnt) grow = cnt - 1;
      aSrc[q] = act + (size_t)(base + grow) * NINTER + swz;
      bSrc[q] = w2be + (size_t)(nt * 128 + r) * NINTER + swz;
    }
  }

  for (int k0 = 0; k0 < NINTER; k0 += 64) {
    if constexpr (BF) {
#pragma unroll
      for (int q = 0; q < 4; ++q) {
        int row0 = wave * 32 + q * 8;
        __builtin_amdgcn_global_load_lds((const AS1 void*)(aSrc[q] + k0), (AS3 void*)&lA[row0 * 64], 16, 0, 0);
        __builtin_amdgcn_global_load_lds((const AS1 void*)(bSrc[q] + k0), (AS3 void*)&lB[row0 * 64], 16, 0, 0);
      }
    } else {
#pragma unroll
      for (int c4 = 0; c4 < 4; ++c4) {
        int cid = c4 * 256 + tid;
        int row = cid >> 3, k8 = cid & 7;
        int grow = mt * 128 + row;
        if (grow >= cnt) grow = cnt - 1;
        s16x8 v = *(const s16x8*)(act + (size_t)(base + grow) * NINTER + k0 + k8 * 8);
        *(s16x8*)&lA[row * 64 + ((k8 ^ (row & 7)) * 8)] = v;
      }
#pragma unroll
      for (int c4 = 0; c4 < 4; ++c4) {
        int cid = c4 * 256 + tid;
        int row = cid >> 3, k8 = cid & 7;
        const float* s = w2e + (size_t)(nt * 128 + row) * NINTER + k0 + k8 * 8;
        float4 f0 = *(const float4*)s;
        float4 f1 = *(const float4*)(s + 4);
        *(s16x8*)&lB[row * 64 + ((k8 ^ (row & 7)) * 8)] = pack8(f0, f1);
      }
    }
    __syncthreads();
#pragma unroll
    for (int kk = 0; kk < 2; ++kk) {
      s16x8 af[4], bf[4];
      int chunk = kk * 4 + lhi;
#pragma unroll
      for (int i = 0; i < 4; ++i) {
        int r = wm * 64 + i * 16 + lrow;
        af[i] = *(const s16x8*)&lA[r * 64 + ((chunk ^ (r & 7)) * 8)];
      }
#pragma unroll
      for (int j = 0; j < 4; ++j) {
        int r = wn * 64 + j * 16 + lrow;
        bf[j] = *(const s16x8*)&lB[r * 64 + ((chunk ^ (r & 7)) * 8)];
      }
#pragma unroll
      for (int i = 0; i < 4; ++i)
#pragma unroll
        for (int j = 0; j < 4; ++j)
          acc[i][j] = __builtin_amdgcn_mfma_f32_16x16x32_bf16(af[i], bf[j], acc[i][j], 0, 0, 0);
    }
    __syncthreads();
  }
#pragma unroll
  for (int i = 0; i < 4; ++i) {
#pragma unroll
    for (int q = 0; q < 4; ++q) {
      int r = wm * 64 + i * 16 + lhi * 4 + q;
      int grow = mt * 128 + r;
      if (grow < cnt) {
        int p = list[base + grow];
        int m = p >> 1;
        float wgt = tw[p];
#pragma unroll
        for (int j = 0; j < 4; ++j) {
          int col = nt * 128 + wn * 64 + j * 16 + lrow;
          atomicAdd(&out[(size_t)m * KDIM + col], wgt * acc[i][j][q]);
        }
      }
    }
  }
}

// standalone route kernel for the fallback path
__global__ __launch_bounds__(512) void route_k(const int* __restrict__ ids,
                                               int* __restrict__ off,
                                               int* __restrict__ list) {
  __shared__ int sids[NPAIR];
  __shared__ int scnt[64][8];
  __shared__ int sstart[64][8];
  __shared__ int s_is64;
  int tid = threadIdx.x;
  if (tid == 0) s_is64 = 1;
  __syncthreads();
  for (int i = tid; i < NPAIR / 2; i += 512)
    if (ids[2 * i + 1] != 0) s_is64 = 0;
  __syncthreads();
  int is64 = s_is64;
  for (int i = tid; i < NPAIR; i += 512) {
    int e = is64 ? ids[2 * i] : ids[i];
    if (e < 0) e = 0; if (e > 7) e = 7;
    sids[i] = e;
  }
  if (tid < 64)
    for (int e = 0; e < 8; ++e) scnt[tid][e] = 0;
  __syncthreads();
  if (tid < 64) {
    int b0 = tid * 128;
    for (int i = 0; i < 128; ++i) ++scnt[tid][sids[b0 + i]];
  }
  __syncthreads();
  if (tid == 0) {
    int tot = 0;
    for (int e = 0; e < 8; ++e) {
      off[e] = tot;
      for (int c = 0; c < 64; ++c) { sstart[c][e] = tot; tot += scnt[c][e]; }
    }
    off[8] = tot;
  }
  __syncthreads();
  if (tid < 64) {
    int b0 = tid * 128;
    for (int i = 0; i < 128; ++i) {
      int p = b0 + i;
      int e = sids[p];
      list[sstart[tid][e]++] = p;
    }
  }
}

extern "C" void kernel_launch(void* const* d_in, const int* in_sizes, int n_in,
                              void* d_out, int out_size, void* d_ws, size_t ws_size,
                              hipStream_t stream) {
  const float* a1 = (const float*)d_in[0];
  const float* w1 = (const float*)d_in[1];
  const float* w2 = (const float*)d_in[2];
  const float* tw = (const float*)d_in[3];
  const int*   ids = (const int*)d_in[4];
  float* out = (float*)d_out;

  int* off  = (int*)d_ws;
  int* list = off + 16;
  unsigned short* act = (unsigned short*)((char*)d_ws + 65536);
  size_t actB = (size_t)NPAIR * NINTER * 2;
  unsigned short* a1b = (unsigned short*)((char*)act + actB);
  size_t a1B = (size_t)MTOK * KDIM * 2;
  unsigned short* w1b = (unsigned short*)((char*)a1b + a1B);
  size_t w1B = (size_t)NEXP * 2 * NINTER * KDIM * 2;
  unsigned short* w2b = (unsigned short*)((char*)w1b + w1B);
  size_t w2B = (size_t)NEXP * KDIM * NINTER * 2;
  size_t need = 65536 + actB + a1B + w1B + w2B;

  hipMemsetAsync(d_out, 0, (size_t)MTOK * KDIM * sizeof(float), stream);

  if (ws_size >= need) {
    routecvt_k<<<4096, 256, 0, stream>>>(ids, off, list, a1, a1b, w1, w1b);
    gemm1_t<1><<<dim3(NINTER / 128, 64, NEXP), 256, 0, stream>>>(a1, a1b, w1, w1b, w2, w2b, off, list, act);
    gemm2_t<1><<<dim3(KDIM / 128, 64, NEXP), 256, 0, stream>>>(act, w2, w2b, off, list, tw, out);
  } else {
    route_k<<<1, 512, 0, stream>>>(ids, off, list);
    gemm1_t<0><<<dim3(NINTER / 128, 64, NEXP), 256, 0, stream>>>(a1, a1b, w1, w1b, w2, w2b, off, list, act);
    gemm2_t<0><<<dim3(KDIM / 128, 64, NEXP), 256, 0, stream>>>(act, w2, w2b, off, list, tw, out);
  }
}